// Round 2
// baseline (3469.453 us; speedup 1.0000x reference)
//
#include <hip/hip_runtime.h>
#include <hip/hip_bf16.h>

// Problem constants (from reference)
constexpr int T  = 6;
constexpr int S  = 66;    // 3*J
constexpr int IN = 256;
constexpr int H  = 8;
constexpr int D  = 32;
constexpr int J  = 22;
constexpr float NEG = -9e15f;
constexpr float SQRT_D = 5.656854249492380195f; // sqrt(32)

// LDS layout (bytes) — total 52,800 <= 64 KB static; 3 blocks/CU (158.4/160 KB)
// stage (per K-chunk): xs f32[66][32] @ 0      (8,448)
//                      wm f32[96][34] @ 8,448  (13,056)  (pad 32->34: 2-way reads = free)
// attn  (overlays)   : sc f32[66][66] @ 0      (17,424)
//                      ao f32[66][32] @ 17,424 (8,448)
// always             : qkv f32[3][66][34] @ 25,872 (26,928)
#define XS_OFF   0
#define WM_OFF   8448
#define SC_OFF   0
#define AO_OFF   17424
#define QKV_OFF  25872
#define SMEM_BYTES 52800

__device__ __forceinline__ float2 bf2f(unsigned int u) {
    // low 16 bits = first bf16, high 16 bits = second bf16
    float2 r;
    r.x = __uint_as_float(u << 16);
    r.y = __uint_as_float(u & 0xffff0000u);
    return r;
}

// Runtime dtype probe: true bf16 data ~N(0,1) has exponent field in ~[100,135];
// f32 data misread as uint16 has interleaved random-mantissa halves whose
// "exponent" field is uniform (incl. 0xFF NaN patterns). Count insane entries.
__device__ __forceinline__ bool probe_is_bf16(const unsigned short* p) {
    int bad = 0;
    #pragma unroll 1
    for (int i = 0; i < 256; ++i) {
        unsigned short e = (p[i] >> 7) & 0xFF;
        bad += (e == 0xFF || e < 100) ? 1 : 0;
    }
    return bad < 16;   // bf16 truth: ~0; f32 truth: ~50
}

__device__ __forceinline__ float ldsc(const void* p, int i, bool isbf) {
    return isbf ? __bfloat162float(((const __hip_bfloat16*)p)[i])
                : ((const float*)p)[i];
}

__global__ __launch_bounds__(256, 3)
void mha_fused_kernel(const void* __restrict__ xv,
                      const void* __restrict__ Wqv, const void* __restrict__ bqv,
                      const void* __restrict__ Wkv, const void* __restrict__ bkv,
                      const void* __restrict__ Wvv, const void* __restrict__ bvv,
                      const void* __restrict__ Wcv, const void* __restrict__ bcv,
                      void* __restrict__ outv)
{
    __shared__ __align__(16) unsigned char smem[SMEM_BYTES];

    const int tid = threadIdx.x;
    const int bth = blockIdx.x;          // [0, 512*6*8)
    const int h   = bth & 7;
    const int bt  = bth >> 3;            // b*T + t

    const bool isbf = probe_is_bf16((const unsigned short*)xv);

    float* qkv = (float*)(smem + QKV_OFF);   // [3][66][34]
    float* sc  = (float*)(smem + SC_OFF);    // [66][66]
    float* ao  = (float*)(smem + AO_OFF);    // [66][32]

    // ---------------- Phase 1+2: q,k,v projections, K streamed in 8 chunks of 32 -----
    const int d  = tid & 31;
    const int sg = tid >> 5;             // 0..7
    const int s0 = sg * 9;               // 9 rows/thread (66 padded to 72)

    int srow[9];
    #pragma unroll
    for (int r = 0; r < 9; ++r) {
        int s = s0 + r;
        srow[r] = (s < 66 ? s : 65) * 16;   // float2-unit row offset in xs
    }

    float acc[3][9];
    #pragma unroll
    for (int m = 0; m < 3; ++m)
        #pragma unroll
        for (int r = 0; r < 9; ++r) acc[m][r] = 0.f;

    for (int kq = 0; kq < 8; ++kq) {
        __syncthreads();   // protect xs/wm from previous iteration's readers

        if (isbf) {
            const __hip_bfloat16* xb = (const __hip_bfloat16*)xv;
            // xs: 66 rows x 32 bf16 = 264 uint4 (8 bf16 each) -> expand to f32
            for (int u = tid; u < 264; u += 256) {
                int s = u >> 2, c = u & 3;
                uint4 w = *(const uint4*)(xb + (size_t)(bt * S + s) * IN + kq * 32 + c * 8);
                float2 a0 = bf2f(w.x), a1 = bf2f(w.y), a2 = bf2f(w.z), a3 = bf2f(w.w);
                float* dst = (float*)(smem + XS_OFF) + s * 32 + c * 8;  // 16B-aligned
                ((float4*)dst)[0] = make_float4(a0.x, a0.y, a1.x, a1.y);
                ((float4*)dst)[1] = make_float4(a2.x, a2.y, a3.x, a3.y);
            }
            // wm: 96 rows x 32 bf16 = 384 uint4
            for (int u = tid; u < 384; u += 256) {
                int row = u >> 2, c = u & 3;
                int m = row >> 5, dd = row & 31;
                const __hip_bfloat16* Wm = (m == 0) ? (const __hip_bfloat16*)Wqv
                                         : (m == 1) ? (const __hip_bfloat16*)Wkv
                                                    : (const __hip_bfloat16*)Wvv;
                uint4 w = *(const uint4*)(Wm + (size_t)(h * 32 + dd) * IN + kq * 32 + c * 8);
                float2 a0 = bf2f(w.x), a1 = bf2f(w.y), a2 = bf2f(w.z), a3 = bf2f(w.w);
                float* dst = (float*)(smem + WM_OFF) + row * 34 + c * 8; // 8B-aligned
                ((float2*)dst)[0] = a0; ((float2*)dst)[1] = a1;
                ((float2*)dst)[2] = a2; ((float2*)dst)[3] = a3;
            }
        } else {
            const float* xf32 = (const float*)xv;
            // xs: 66 rows x 32 f32 = 528 float4
            for (int u = tid; u < 528; u += 256) {
                int s = u >> 3, c = u & 7;
                float4 w = *(const float4*)(xf32 + (size_t)(bt * S + s) * IN + kq * 32 + c * 4);
                float* dst = (float*)(smem + XS_OFF) + s * 32 + c * 4;  // 16B-aligned
                *(float4*)dst = w;
            }
            // wm: 96 rows x 32 f32 = 768 float4
            for (int u = tid; u < 768; u += 256) {
                int row = u >> 3, c = u & 7;
                int m = row >> 5, dd = row & 31;
                const float* Wm = (m == 0) ? (const float*)Wqv
                                : (m == 1) ? (const float*)Wkv
                                           : (const float*)Wvv;
                float4 w = *(const float4*)(Wm + (size_t)(h * 32 + dd) * IN + kq * 32 + c * 4);
                float* dst = (float*)(smem + WM_OFF) + row * 34 + c * 4; // 8B-aligned
                ((float2*)dst)[0] = make_float2(w.x, w.y);
                ((float2*)dst)[1] = make_float2(w.z, w.w);
            }
        }
        __syncthreads();

        const float2* xs2 = (const float2*)(smem + XS_OFF);  // [66][16]
        const float2* wm2 = (const float2*)(smem + WM_OFF);  // row stride 17 float2

        #pragma unroll 4
        for (int ipp = 0; ipp < 16; ++ipp) {   // 2 k-values per step
            float2 xf[9];
            #pragma unroll
            for (int r = 0; r < 9; ++r) xf[r] = xs2[srow[r] + ipp];   // broadcast
            #pragma unroll
            for (int m = 0; m < 3; ++m) {
                float2 w = wm2[(m * 32 + d) * 17 + ipp];   // 2-way across lanes: free
                #pragma unroll
                for (int r = 0; r < 9; ++r) {
                    float t = acc[m][r];
                    t = fmaf(xf[r].x, w.x, t);
                    t = fmaf(xf[r].y, w.y, t);
                    acc[m][r] = t;
                }
            }
        }
    }

    // bias + relu(v), write qkv
    {
        const float bqa = ldsc(bqv, h * 32 + d, isbf);
        const float bka = ldsc(bkv, h * 32 + d, isbf);
        const float bva = ldsc(bvv, h * 32 + d, isbf);
        #pragma unroll
        for (int m = 0; m < 3; ++m) {
            float bias = (m == 0) ? bqa : (m == 1) ? bka : bva;
            #pragma unroll
            for (int r = 0; r < 9; ++r) {
                int s = s0 + r;
                if (s < 66) {
                    float v = acc[m][r] + bias;
                    if (m == 2) v = fmaxf(v, 0.f);
                    qkv[(m * 66 + s) * 34 + d] = v;
                }
            }
        }
    }
    __syncthreads();  // qkv ready; xs/wm dead -> sc/ao may overlay

    // ---------------- Phase 3: scores = mask * (q k^T / sqrt(D)) ----------------------
    for (int u = tid; u < S * S; u += 256) {
        int qs = u / 66, kk = u - qs * 66;
        float v = 0.f;
        bool masked = (qs < J && kk >= 2 * J) || (qs >= 2 * J && kk < J);
        if (!masked) {
            const float2* qrow = (const float2*)(qkv + (0 * 66 + qs) * 34);
            const float2* krow = (const float2*)(qkv + (1 * 66 + kk) * 34);
            float a = 0.f;
            #pragma unroll
            for (int dd = 0; dd < 16; ++dd) {
                float2 qq = qrow[dd], kv = krow[dd];
                a = fmaf(qq.x, kv.x, a);
                a = fmaf(qq.y, kv.y, a);
            }
            v = a / SQRT_D;
        }
        sc[u] = v;
    }
    __syncthreads();

    // ---------------- Phase 4: prune + softmax per row (reference semantics) ----------
    if (tid < 66) {
        float* row = sc + tid * 66;
        float m = -INFINITY;
        for (int c = 0; c < 66; ++c) m = fmaxf(m, row[c]);
        const float thr = m / 9.0f;
        float rmax = -INFINITY;
        for (int c = 0; c < 66; ++c) {
            float sv = row[c];
            float pr = (fabsf(sv) <= thr) ? NEG : sv;
            row[c] = pr;
            rmax = fmaxf(rmax, pr);
        }
        float sum = 0.f;
        for (int c = 0; c < 66; ++c) {
            float e = __expf(row[c] - rmax);   // all-pruned row -> uniform (matches ref)
            sum += e;
            row[c] = e;
        }
        const float inv = 1.0f / sum;
        for (int c = 0; c < 66; ++c) row[c] *= inv;
    }
    __syncthreads();

    // ---------------- Phase 5: ao = attn @ v ------------------------------------------
    for (int u = tid; u < S * D; u += 256) {
        int qs = u >> 5, dd = u & 31;
        const float* arow = sc + qs * 66;
        float a = 0.f;
        for (int kk = 0; kk < 66; ++kk)
            a = fmaf(arow[kk], qkv[(2 * 66 + kk) * 34 + dd], a);
        ao[qs * 32 + dd] = a;
    }
    __syncthreads();

    // ---------------- Phase 6: cls projection over S, write output --------------------
    for (int u = tid; u < J * D; u += 256) {
        int j = u >> 5, dd = u & 31;
        float a = ldsc(bcv, j, isbf);
        for (int s = 0; s < 66; ++s)
            a = fmaf(ldsc(Wcv, j * 66 + s, isbf), ao[s * 32 + dd], a);
        size_t o = (size_t)(bt * J + j) * (H * D) + h * 32 + dd;
        if (isbf) ((__hip_bfloat16*)outv)[o] = __float2bfloat16(a);
        else      ((float*)outv)[o] = a;
    }
}

extern "C" void kernel_launch(void* const* d_in, const int* in_sizes, int n_in,
                              void* d_out, int out_size, void* d_ws, size_t ws_size,
                              hipStream_t stream) {
    const int B = 512;
    dim3 grid(B * T * H), block(256);
    hipLaunchKernelGGL(mha_fused_kernel, grid, block, 0, stream,
                       d_in[0], d_in[1], d_in[2], d_in[3], d_in[4],
                       d_in[5], d_in[6], d_in[7], d_in[8], d_out);
}

// Round 4
// 1747.144 us; speedup vs baseline: 1.9858x; 1.9858x over previous
//
#include <hip/hip_runtime.h>
#include <hip/hip_bf16.h>

// Problem constants (from reference). All I/O is float32 (verified R2).
constexpr int T  = 6;
constexpr int S  = 66;    // 3*J
constexpr int IN = 256;
constexpr int H  = 8;
constexpr int D  = 32;
constexpr int J  = 22;
constexpr float NEG = -9e15f;
constexpr float SQRT_D = 5.656854249492380195f; // sqrt(32)

// LDS layout (bytes) — total 52,800; 3 blocks/CU (158,400 <= 163,840)
// proj stage (per 64-K-chunk, x4), split-bf16 hi/lo:
//   xh bf16[80][72] @ 0       (11,520)   rows 66..79 never written (discarded D rows)
//   xl bf16[80][72] @ 11,520  (11,520)   end 23,040
//   wh bf16[96][72] @ 23,040  (13,824)   end 36,864
//   wl bf16[96][72] @ 36,864  (13,824)   end 50,688   (pad 64->72: b128 reads 2-way = free)
// attn phase (overlays, after barriers):
//   qkv f32[3][66][34] @ 0      (26,928)
//   sc  f32[66][66]    @ 26,928 (17,424)  end 44,352
//   ao  f32[66][32]    @ 44,352 ( 8,448)  end 52,800
#define XH_OFF   0
#define XL_OFF   11520
#define WH_OFF   23040
#define WL_OFF   36864
#define QKV_OFF  0
#define SC_OFF   26928
#define AO_OFF   44352
#define SMEM_BYTES 52800

typedef float f32x4  __attribute__((ext_vector_type(4)));
typedef short bf16x8 __attribute__((ext_vector_type(8)));

// split two f32 into packed bf16 hi (rne) and bf16 lo (rne of residual)
__device__ __forceinline__ void split2(float a, float b, unsigned& hi, unsigned& lo) {
    unsigned ua = __float_as_uint(a), ub = __float_as_uint(b);
    unsigned ha = (ua + 0x7FFFu + ((ua >> 16) & 1u)) >> 16;
    unsigned hb = (ub + 0x7FFFu + ((ub >> 16) & 1u)) >> 16;
    hi = ha | (hb << 16);
    float ra = a - __uint_as_float(ha << 16);
    float rb = b - __uint_as_float(hb << 16);
    unsigned la = __float_as_uint(ra), lb = __float_as_uint(rb);
    la = (la + 0x7FFFu + ((la >> 16) & 1u)) >> 16;
    lb = (lb + 0x7FFFu + ((lb >> 16) & 1u)) >> 16;
    lo = la | (lb << 16);
}

__global__ __launch_bounds__(256, 3)
void mha_fused_kernel(const float* __restrict__ x,
                      const float* __restrict__ Wq, const float* __restrict__ bq,
                      const float* __restrict__ Wk, const float* __restrict__ bk,
                      const float* __restrict__ Wv, const float* __restrict__ bv,
                      const float* __restrict__ Wc, const float* __restrict__ bc,
                      float* __restrict__ out)
{
    __shared__ __align__(16) unsigned char smem[SMEM_BYTES];

    const int tid = threadIdx.x;
    const int bth = blockIdx.x;          // [0, 512*6*8)
    const int h   = bth & 7;
    const int bt  = bth >> 3;            // b*T + t

    const int wid  = tid >> 6;           // wave 0..3
    const int lane = tid & 63;
    const int l15  = lane & 15;
    const int quad = lane >> 4;

    float* qkv = (float*)(smem + QKV_OFF);   // [3][66][34]
    float* sc  = (float*)(smem + SC_OFF);    // [66][66]
    float* ao  = (float*)(smem + AO_OFF);    // [66][32]

    // ---------------- Phase 1: q,k,v projections via split-bf16 MFMA ------------------
    // 30 tile-jobs: (mat 0..2) x (mtile 0..4) x (ntile 0..1); wave w owns j = w, w+4, ...
    // D = A*B via hi*hi + hi*lo + lo*hi (3 MFMA, shared f32 accumulator) => ~fp32 exact.
    f32x4 accs[8];
    #pragma unroll
    for (int jj = 0; jj < 8; ++jj) accs[jj] = (f32x4){0.f, 0.f, 0.f, 0.f};

    for (int chunk = 0; chunk < 4; ++chunk) {    // K = 4 x 64
        __syncthreads();   // protect stage buffers from previous chunk's readers

        // stage x tile: 66 rows x 64 f32 -> hi/lo bf16. 1056 float4 loads.
        {
            const float* xg = x + (size_t)bt * S * IN + chunk * 64;
            for (int u = tid; u < 1056; u += 256) {
                int s = u >> 4, c = u & 15;
                float4 v = *(const float4*)(xg + (size_t)s * IN + c * 4);
                uint2 hi, lo;
                split2(v.x, v.y, hi.x, lo.x);
                split2(v.z, v.w, hi.y, lo.y);
                ((uint2*)(smem + XH_OFF + s * 144))[c] = hi;
                ((uint2*)(smem + XL_OFF + s * 144))[c] = lo;
            }
        }
        // stage W slices: 3 mats x 32 rows x 64 f32 -> hi/lo bf16. 1536 float4 loads.
        for (int u = tid; u < 1536; u += 256) {
            int row = u >> 4, c = u & 15;
            int m = row >> 5, dd = row & 31;
            const float* Wm = (m == 0) ? Wq : (m == 1) ? Wk : Wv;
            float4 v = *(const float4*)(Wm + (size_t)(h * 32 + dd) * IN + chunk * 64 + c * 4);
            uint2 hi, lo;
            split2(v.x, v.y, hi.x, lo.x);
            split2(v.z, v.w, hi.y, lo.y);
            ((uint2*)(smem + WH_OFF + row * 144))[c] = hi;
            ((uint2*)(smem + WL_OFF + row * 144))[c] = lo;
        }
        __syncthreads();

        const short* xh = (const short*)(smem + XH_OFF);
        const short* xl = (const short*)(smem + XL_OFF);
        const short* wh = (const short*)(smem + WH_OFF);
        const short* wl = (const short*)(smem + WL_OFF);

        for (int jj = 0; jj < 8; ++jj) {
            int j = wid + 4 * jj;
            if (j >= 30) break;                      // wave-uniform
            int mat = j / 10, rr = j - mat * 10;
            int mtile = rr >> 1, ntile = rr & 1;
            int arow = (mtile * 16 + l15) * 72 + quad * 8;
            int brow = (mat * 32 + ntile * 16 + l15) * 72 + quad * 8;
            #pragma unroll
            for (int kk = 0; kk < 2; ++kk) {
                bf16x8 ah = *(const bf16x8*)(xh + arow + kk * 32);
                bf16x8 al = *(const bf16x8*)(xl + arow + kk * 32);
                bf16x8 bh = *(const bf16x8*)(wh + brow + kk * 32);
                bf16x8 bl = *(const bf16x8*)(wl + brow + kk * 32);
                accs[jj] = __builtin_amdgcn_mfma_f32_16x16x32_bf16(ah, bh, accs[jj], 0, 0, 0);
                accs[jj] = __builtin_amdgcn_mfma_f32_16x16x32_bf16(ah, bl, accs[jj], 0, 0, 0);
                accs[jj] = __builtin_amdgcn_mfma_f32_16x16x32_bf16(al, bh, accs[jj], 0, 0, 0);
            }
        }
    }
    __syncthreads();   // stage buffers dead; qkv may overlay

    // write qkv with bias (+relu for v). D layout: col = l15, row = quad*4 + reg.
    for (int jj = 0; jj < 8; ++jj) {
        int j = wid + 4 * jj;
        if (j >= 30) break;
        int mat = j / 10, rr = j - mat * 10;
        int mtile = rr >> 1, ntile = rr & 1;
        int dd = ntile * 16 + l15;
        const float* bias_p = (mat == 0) ? bq : (mat == 1) ? bk : bv;
        float bias = bias_p[h * 32 + dd];
        #pragma unroll
        for (int reg = 0; reg < 4; ++reg) {
            int s = mtile * 16 + quad * 4 + reg;
            if (s < 66) {
                float v = accs[jj][reg] + bias;
                if (mat == 2) v = fmaxf(v, 0.f);
                qkv[(mat * 66 + s) * 34 + dd] = v;
            }
        }
    }
    __syncthreads();

    // ---------------- Phase 3: scores = mask * (q k^T / sqrt(D)) ----------------------
    for (int u = tid; u < S * S; u += 256) {
        int qs = u / 66, kk = u - qs * 66;
        float v = 0.f;
        bool masked = (qs < J && kk >= 2 * J) || (qs >= 2 * J && kk < J);
        if (!masked) {
            const float2* qrow = (const float2*)(qkv + (0 * 66 + qs) * 34);
            const float2* krow = (const float2*)(qkv + (1 * 66 + kk) * 34);
            float a = 0.f;
            #pragma unroll
            for (int dd = 0; dd < 16; ++dd) {
                float2 qq = qrow[dd], kv = krow[dd];
                a = fmaf(qq.x, kv.x, a);
                a = fmaf(qq.y, kv.y, a);
            }
            v = a / SQRT_D;
        }
        sc[u] = v;
    }
    __syncthreads();

    // ---------------- Phase 4: prune + softmax per row (reference semantics) ----------
    if (tid < 66) {
        float* row = sc + tid * 66;
        float m = -INFINITY;
        for (int c = 0; c < 66; ++c) m = fmaxf(m, row[c]);
        const float thr = m / 9.0f;
        float rmax = -INFINITY;
        for (int c = 0; c < 66; ++c) {
            float sv = row[c];
            float pr = (fabsf(sv) <= thr) ? NEG : sv;
            row[c] = pr;
            rmax = fmaxf(rmax, pr);
        }
        float sum = 0.f;
        for (int c = 0; c < 66; ++c) {
            float e = __expf(row[c] - rmax);   // all-pruned row -> uniform (matches ref)
            sum += e;
            row[c] = e;
        }
        const float inv = 1.0f / sum;
        for (int c = 0; c < 66; ++c) row[c] *= inv;
    }
    __syncthreads();

    // ---------------- Phase 5: ao = attn @ v (float2 over d) --------------------------
    for (int u = tid; u < S * 16; u += 256) {
        int qs = u >> 4, d2 = u & 15;
        const float* arow = sc + qs * 66;
        const float* vb   = qkv + 132 * 34 + d2 * 2;
        float ax = 0.f, ay = 0.f;
        for (int kk = 0; kk < 66; ++kk) {
            float w = arow[kk];
            float2 vv = *(const float2*)(vb + kk * 34);
            ax = fmaf(w, vv.x, ax);
            ay = fmaf(w, vv.y, ay);
        }
        *(float2*)(ao + qs * 32 + d2 * 2) = make_float2(ax, ay);
    }
    __syncthreads();

    // ---------------- Phase 6: cls projection over S, write output --------------------
    for (int u = tid; u < J * D; u += 256) {
        int j = u >> 5, dd = u & 31;
        float a = bc[j];
        for (int s = 0; s < 66; ++s)
            a = fmaf(Wc[j * 66 + s], ao[s * 32 + dd], a);
        size_t o = (size_t)(bt * J + j) * (H * D) + h * 32 + dd;
        out[o] = a;
    }
}

extern "C" void kernel_launch(void* const* d_in, const int* in_sizes, int n_in,
                              void* d_out, int out_size, void* d_ws, size_t ws_size,
                              hipStream_t stream) {
    const float* x  = (const float*)d_in[0];
    const float* Wq = (const float*)d_in[1];
    const float* bq = (const float*)d_in[2];
    const float* Wk = (const float*)d_in[3];
    const float* bk = (const float*)d_in[4];
    const float* Wv = (const float*)d_in[5];
    const float* bv = (const float*)d_in[6];
    const float* Wc = (const float*)d_in[7];
    const float* bc = (const float*)d_in[8];
    float* out = (float*)d_out;

    const int B = 512;
    dim3 grid(B * T * H), block(256);
    hipLaunchKernelGGL(mha_fused_kernel, grid, block, 0, stream,
                       x, Wq, bq, Wk, bk, Wv, bv, Wc, bc, out);
}